// Round 13
// baseline (233.351 us; speedup 1.0000x reference)
//
#include <hip/hip_runtime.h>
#include <hip/hip_bf16.h>

#define NPTS 200000
#define NVOX 60000
#define NB 4
#define KK 27

// ---- mask encoding: 0 = uint8 bool, 1 = int32, 2 = float32 ----
__device__ __forceinline__ float get_mask(const void* nm, int fl, long i) {
    if (fl == 0) return ((const unsigned char*)nm)[i] ? 1.0f : 0.0f;
    if (fl == 1) return ((const int*)nm)[i] ? 1.0f : 0.0f;
    return ((const float*)nm)[i];
}

// ---- init: zero scratch + detect mask encoding (block 0) ----
__global__ void k_init(float* zbase, int nz, const unsigned int* nm, int* flag) {
    for (int i = blockIdx.x * 256 + threadIdx.x; i < nz; i += gridDim.x * 256)
        zbase[i] = 0.f;
    if (blockIdx.x == 0) {
        __shared__ int cntF, cntI;
        if (threadIdx.x == 0) { cntF = 0; cntI = 0; }
        __syncthreads();
        int f = 0, i1 = 0;
        for (int i = threadIdx.x; i < 1024; i += 256) {
            unsigned int v = nm[i];
            if (v == 0x3f800000u) f++;
            if (v == 1u) i1++;
        }
        atomicAdd(&cntF, f); atomicAdd(&cntI, i1);
        __syncthreads();
        if (threadIdx.x == 0)
            *flag = (cntF > 100) ? 2 : ((cntI > 100) ? 1 : 0);
    }
}

// ---- voxelize: scatter-add points into voxels ----
__global__ void k_scatter(const float4* __restrict__ feat, const int* __restrict__ p2v,
                          float* cnt, float* vox) {
    int p = blockIdx.x * 256 + threadIdx.x;
    if (p >= NPTS) return;
    int v = p2v[p];
    float4 f = feat[p];
    atomicAdd(&cnt[v], 1.0f);
    atomicAdd(&vox[v * 4 + 0], f.x);
    atomicAdd(&vox[v * 4 + 1], f.y);
    atomicAdd(&vox[v * 4 + 2], f.z);
    atomicAdd(&vox[v * 4 + 3], f.w);
}

// ---- voxdiv: coalesced divide ----
__global__ void k_voxdiv(float* vox, const float* __restrict__ cnt) {
    int n = blockIdx.x * 256 + threadIdx.x;
    if (n >= NVOX) return;
    float inv = 1.0f / fmaxf(cnt[n], 1.0f);
    float4* vp = (float4*)(vox + n * 4);
    float4 v = *vp;
    v.x *= inv; v.y *= inv; v.z *= inv; v.w *= inv;
    *vp = v;
}

// ---- conv1: Cin=4 -> Cout=32; 256 thr = 64 vox x 4 kc-waves ----
__global__ __launch_bounds__(256) void k_conv1(
        const float* __restrict__ vox, const float* __restrict__ W1,
        const float* __restrict__ g1, const float* __restrict__ b1,
        const int* __restrict__ nidx, const void* __restrict__ nmask,
        const int* __restrict__ flag, float* __restrict__ h1) {
    __shared__ float part[3][64][33];
    int tid = threadIdx.x;
    int lane = tid & 63;
    int kc = __builtin_amdgcn_readfirstlane(tid >> 6);   // wave-uniform chunk
    int v = blockIdx.x * 64 + lane;
    int vc = v < NVOX ? v : NVOX - 1;
    int fl = *flag;
    int k0 = kc * 7;
    int k1 = (kc == 3) ? KK : k0 + 7;   // 7,7,7,6
    float acc[32];
#pragma unroll
    for (int d = 0; d < 32; d++) acc[d] = 0.f;
#pragma unroll 1
    for (int k = k0; k < k1; ++k) {
        int idx = nidx[k * NVOX + vc];
        float m = get_mask(nmask, fl, (long)k * NVOX + vc);
        float4 r = ((const float4*)vox)[idx];
        const float* wk = W1 + k * 128;   // wave-uniform -> s_load (3.4KB, K$-resident)
#pragma unroll
        for (int c = 0; c < 4; c++) {
            float rc = (c == 0 ? r.x : c == 1 ? r.y : c == 2 ? r.z : r.w) * m;
            const float* wc = wk + c * 32;
#pragma unroll
            for (int d = 0; d < 32; d++) acc[d] = fmaf(rc, wc[d], acc[d]);
        }
    }
    if (kc > 0) {
#pragma unroll
        for (int d = 0; d < 32; d++) part[kc - 1][lane][d] = acc[d];
    }
    __syncthreads();
    if (kc == 0 && v < NVOX) {
        float o[32];
#pragma unroll
        for (int d = 0; d < 32; d++) {
            float s = acc[d] + part[0][lane][d] + part[1][lane][d] + part[2][lane][d];
            o[d] = fmaxf(s * g1[d] + b1[d], 0.f);
        }
        float4* op = (float4*)(h1 + (size_t)v * 32);
#pragma unroll
        for (int qq = 0; qq < 8; qq++)
            op[qq] = make_float4(o[qq * 4], o[qq * 4 + 1], o[qq * 4 + 2], o[qq * 4 + 3]);
    }
}

// ---- conv2: 256 thr = 64 vox x 4 kc-waves; WAVE-PRIVATE LDS weight staging ----
// The 65-77us plateau across r3/r9/r10/r12 is the per-CU SCALAR pipe: every wave
// s_loads 4KB/k with disjoint kc chunks (32KB live vs 16KB K$ -> ~all miss,
// serialized). r11's LDS staging fixed the path but its 14 block barriers forced
// lockstep. Here each wave stages W2[k] into its OWN wbuf[kc] (vector loads +
// ds_write, wave-internal lgkmcnt ordering only -> NO barriers in the k-loop),
// then FMA reads uniform broadcast ds_read_b128. Waves slip freely; scalar pipe
// idle; weight stream rides the deep vector+DS pipes.
__global__ __launch_bounds__(256) void k_conv2(
        const float* __restrict__ h1, const float* __restrict__ W2,
        const float* __restrict__ g2, const float* __restrict__ b2,
        const int* __restrict__ nidx, const void* __restrict__ nmask,
        const int* __restrict__ flag, float* __restrict__ h2) {
    __shared__ float part[3][64][33];   // 25.3KB
    __shared__ float wbuf[4][1024];     // 16KB: PER-WAVE weight tile (kc-indexed)
    int tid = threadIdx.x;
    int lane = tid & 63;
    int kc = __builtin_amdgcn_readfirstlane(tid >> 6);   // wave-uniform chunk
    int v = blockIdx.x * 64 + lane;
    int vc = v < NVOX ? v : NVOX - 1;
    int fl = *flag;
    int k0 = kc * 7;
    int k1 = (kc == 3) ? KK : k0 + 7;   // 7,7,7,6
    float* wb = &wbuf[kc][0];
    float4* wb4 = (float4*)wb;
    float acc[32];
#pragma unroll
    for (int d = 0; d < 32; d++) acc[d] = 0.f;

#pragma unroll 1
    for (int k = k0; k < k1; ++k) {
        // ---- stage W2[k] (4KB) into my wave's buffer: coalesced vector loads ----
        {
            const float4* wsrc = (const float4*)(W2 + (size_t)k * 1024);
            float4 s0 = wsrc[lane];
            float4 s1 = wsrc[lane + 64];
            wb4[lane]      = s0;
            wb4[lane + 64] = s1;
            float4 s2 = wsrc[lane + 128];
            float4 s3 = wsrc[lane + 192];
            wb4[lane + 128] = s2;
            wb4[lane + 192] = s3;
        }
        int idx = nidx[k * NVOX + vc];
        float m = get_mask(nmask, fl, (long)k * NVOX + vc);
        const float4* rp = (const float4*)(h1 + (size_t)idx * 32);
        // phase 1: input channels 0..15 (compiler inserts lgkmcnt before reads)
        {
            float4 rq[4] = { rp[0], rp[1], rp[2], rp[3] };
#pragma unroll
            for (int c = 0; c < 16; c++) {
                float4 aq = rq[c >> 2];
                float rc = ((c & 3) == 0 ? aq.x : (c & 3) == 1 ? aq.y :
                            (c & 3) == 2 ? aq.z : aq.w) * m;
                const float4* wc4 = (const float4*)(wb + c * 32);
#pragma unroll
                for (int q = 0; q < 8; q++) {   // uniform ds_read_b128 broadcast
                    float4 w = wc4[q];
                    acc[q * 4 + 0] = fmaf(rc, w.x, acc[q * 4 + 0]);
                    acc[q * 4 + 1] = fmaf(rc, w.y, acc[q * 4 + 1]);
                    acc[q * 4 + 2] = fmaf(rc, w.z, acc[q * 4 + 2]);
                    acc[q * 4 + 3] = fmaf(rc, w.w, acc[q * 4 + 3]);
                }
            }
        }
        // phase 2: input channels 16..31
        {
            float4 rq[4] = { rp[4], rp[5], rp[6], rp[7] };
#pragma unroll
            for (int c = 16; c < 32; c++) {
                float4 aq = rq[(c >> 2) - 4];
                float rc = ((c & 3) == 0 ? aq.x : (c & 3) == 1 ? aq.y :
                            (c & 3) == 2 ? aq.z : aq.w) * m;
                const float4* wc4 = (const float4*)(wb + c * 32);
#pragma unroll
                for (int q = 0; q < 8; q++) {
                    float4 w = wc4[q];
                    acc[q * 4 + 0] = fmaf(rc, w.x, acc[q * 4 + 0]);
                    acc[q * 4 + 1] = fmaf(rc, w.y, acc[q * 4 + 1]);
                    acc[q * 4 + 2] = fmaf(rc, w.z, acc[q * 4 + 2]);
                    acc[q * 4 + 3] = fmaf(rc, w.w, acc[q * 4 + 3]);
                }
            }
        }
    }
    if (kc > 0) {
#pragma unroll
        for (int d = 0; d < 32; d++) part[kc - 1][lane][d] = acc[d];
    }
    __syncthreads();
    if (kc == 0 && v < NVOX) {
        float o[32];
#pragma unroll
        for (int d = 0; d < 32; d++) {
            float s = acc[d] + part[0][lane][d] + part[1][lane][d] + part[2][lane][d];
            o[d] = fmaxf(s * g2[d] + b2[d], 0.f);
        }
        float4* op = (float4*)(h2 + (size_t)v * 32);
#pragma unroll
        for (int qq = 0; qq < 8; qq++)
            op[qq] = make_float4(o[qq * 4], o[qq * 4 + 1], o[qq * 4 + 2], o[qq * 4 + 3]);
    }
}

// ---- per-batch pooling: register accumulation, tiny atomic tail ----
__global__ __launch_bounds__(256) void k_pool(
        const float* __restrict__ h2, const int* __restrict__ vb,
        float* bsum, unsigned int* bmax, float* bcnt) {
    __shared__ float ls[NB * 32];
    __shared__ unsigned int lm[NB * 32];
    __shared__ float lc[NB];
    for (int i = threadIdx.x; i < NB * 32; i += 256) { ls[i] = 0.f; lm[i] = 0u; }
    if (threadIdx.x < NB) lc[threadIdx.x] = 0.f;
    __syncthreads();
    int c = threadIdx.x & 31, slot = threadIdx.x >> 5;
    float s0 = 0, s1 = 0, s2 = 0, s3 = 0, m0 = 0, m1 = 0, m2 = 0, m3 = 0;
    float c0 = 0, c1 = 0, c2 = 0, c3 = 0;
    for (int n = blockIdx.x * 8 + slot; n < NVOX; n += gridDim.x * 8) {
        float vv = h2[(size_t)n * 32 + c];
        int b = vb[n];
        s0 += (b == 0) ? vv : 0.f; m0 = (b == 0) ? fmaxf(m0, vv) : m0;
        s1 += (b == 1) ? vv : 0.f; m1 = (b == 1) ? fmaxf(m1, vv) : m1;
        s2 += (b == 2) ? vv : 0.f; m2 = (b == 2) ? fmaxf(m2, vv) : m2;
        s3 += (b == 3) ? vv : 0.f; m3 = (b == 3) ? fmaxf(m3, vv) : m3;
        if (c == 0) {
            c0 += (b == 0) ? 1.f : 0.f; c1 += (b == 1) ? 1.f : 0.f;
            c2 += (b == 2) ? 1.f : 0.f; c3 += (b == 3) ? 1.f : 0.f;
        }
    }
    atomicAdd(&ls[0 * 32 + c], s0); atomicAdd(&ls[1 * 32 + c], s1);
    atomicAdd(&ls[2 * 32 + c], s2); atomicAdd(&ls[3 * 32 + c], s3);
    atomicMax(&lm[0 * 32 + c], __float_as_uint(m0));  // h2 >= 0
    atomicMax(&lm[1 * 32 + c], __float_as_uint(m1));
    atomicMax(&lm[2 * 32 + c], __float_as_uint(m2));
    atomicMax(&lm[3 * 32 + c], __float_as_uint(m3));
    if (c == 0) {
        atomicAdd(&lc[0], c0); atomicAdd(&lc[1], c1);
        atomicAdd(&lc[2], c2); atomicAdd(&lc[3], c3);
    }
    __syncthreads();
    if (threadIdx.x < NB * 32) {
        atomicAdd(&bsum[threadIdx.x], ls[threadIdx.x]);
        atomicMax(&bmax[threadIdx.x], lm[threadIdx.x]);
    }
    if (threadIdx.x < NB) atomicAdd(&bcnt[threadIdx.x], lc[threadIdx.x]);
}

// ---- channel-attention MLP (tiny, 4 batches) ----
__global__ void k_ca(const float* __restrict__ bsum, const unsigned int* __restrict__ bmax,
                     const float* __restrict__ bcnt,
                     const float* __restrict__ w1, const float* __restrict__ b1,
                     const float* __restrict__ w2, const float* __restrict__ b2,
                     float* ca) {
    int b = threadIdx.x;
    if (b >= NB) return;
    float avg[32], mx[32], o[32];
    float inv = 1.0f / fmaxf(bcnt[b], 1.0f);
#pragma unroll
    for (int c = 0; c < 32; c++) {
        avg[c] = bsum[b * 32 + c] * inv;
        mx[c]  = __uint_as_float(bmax[b * 32 + c]);
        o[c] = 0.f;
    }
#pragma unroll
    for (int pass = 0; pass < 2; pass++) {
        float r[8];
#pragma unroll
        for (int j = 0; j < 8; j++) {
            float s = b1[j];
#pragma unroll
            for (int c = 0; c < 32; c++) s += (pass ? mx[c] : avg[c]) * w1[c * 8 + j];
            r[j] = fmaxf(s, 0.f);
        }
#pragma unroll
        for (int d = 0; d < 32; d++) {
            float s = b2[d];
#pragma unroll
            for (int j = 0; j < 8; j++) s += r[j] * w2[j * 32 + d];
            o[d] += s;
        }
    }
#pragma unroll
    for (int d = 0; d < 32; d++)
        ca[b * 32 + d] = 1.0f / (1.0f + expf(-o[d]));
}

// ---- apply channel attention (in place) + build s2 = [mean_c, max_c]; 2 thr/voxel ----
__global__ void k_apply(float* h2, const float* __restrict__ ca,
                        const int* __restrict__ vb, float* __restrict__ s2) {
    int t = blockIdx.x * 256 + threadIdx.x;
    int v = t >> 1, hf = t & 1;
    if (v >= NVOX) return;
    int b = vb[v];
    float4* hp = (float4*)(h2 + (size_t)v * 32) + hf * 4;
    const float4* cp = (const float4*)(ca + b * 32) + hf * 4;
    float sum = 0.f, mx = 0.f;
#pragma unroll
    for (int q = 0; q < 4; q++) {
        float4 h = hp[q]; float4 c = cp[q];
        h.x *= c.x; h.y *= c.y; h.z *= c.z; h.w *= c.w;
        hp[q] = h;
        sum += h.x + h.y + h.z + h.w;
        mx = fmaxf(mx, fmaxf(fmaxf(h.x, h.y), fmaxf(h.z, h.w)));
    }
    sum += __shfl_xor(sum, 1);
    mx = fmaxf(mx, __shfl_xor(mx, 1));
    if (hf == 0) {
        s2[v * 2 + 0] = sum * (1.0f / 32.0f);
        s2[v * 2 + 1] = mx;
    }
}

// ---- spatial attention: 2-ch sparse conv -> sigmoid; 4 thr/voxel ----
__global__ void k_saconv(const float* __restrict__ s2, const float* __restrict__ saW,
                         const int* __restrict__ nidx, const void* __restrict__ nmask,
                         const int* __restrict__ flag, float* __restrict__ sa) {
    __shared__ float w[KK * 2];
    if (threadIdx.x < KK * 2) w[threadIdx.x] = saW[threadIdx.x];
    __syncthreads();
    int t = blockIdx.x * 256 + threadIdx.x;
    int v = t >> 2, q = t & 3;
    if (v >= NVOX) return;
    int fl = *flag;
    float acc = 0.f;
#pragma unroll
    for (int j = 0; j < 7; j++) {
        int k = q + j * 4;
        if (k < KK) {
            int idx = nidx[k * NVOX + v];
            float m = get_mask(nmask, fl, (long)k * NVOX + v);
            float2 s = ((const float2*)s2)[idx];
            acc += m * (s.x * w[k * 2] + s.y * w[k * 2 + 1]);
        }
    }
    acc += __shfl_xor(acc, 1);
    acc += __shfl_xor(acc, 2);
    if (q == 0) sa[v] = 1.0f / (1.0f + expf(-acc));
}

// ---- gather to points, apply sa, classifier; 2 thr/point split over c ----
__global__ __launch_bounds__(256) void k_final(
        const float* __restrict__ h2, const float* __restrict__ sa,
        const int* __restrict__ p2v, const float* __restrict__ clsw,
        const float* __restrict__ clsb, float* __restrict__ out) {
    __shared__ float w[32 * 20];
    __shared__ float bb[20];
    for (int i = threadIdx.x; i < 640; i += 256) w[i] = clsw[i];
    if (threadIdx.x < 20) bb[threadIdx.x] = clsb[threadIdx.x];
    __syncthreads();
    int t = blockIdx.x * 256 + threadIdx.x;
    int p = t >> 1, ch = t & 1;
    if (p >= NPTS) return;
    int v = p2v[p];
    float s = sa[v];
    float acc[20];
#pragma unroll
    for (int j = 0; j < 20; j++) acc[j] = 0.f;
    const float4* hp = (const float4*)(h2 + (size_t)v * 32) + ch * 4;
#pragma unroll
    for (int q = 0; q < 4; q++) {
        float4 h = hp[q];
        int cb = (ch * 16 + q * 4) * 20;
        float z0 = h.x * s, z1 = h.y * s, z2 = h.z * s, z3 = h.w * s;
#pragma unroll
        for (int j = 0; j < 20; j++)
            acc[j] += z0 * w[cb + j] + z1 * w[cb + 20 + j]
                    + z2 * w[cb + 40 + j] + z3 * w[cb + 60 + j];
    }
#pragma unroll
    for (int j = 0; j < 20; j++) acc[j] += __shfl_xor(acc[j], 1);
    if (ch == 0) {
#pragma unroll
        for (int j = 0; j < 20; j++) out[(size_t)p * 20 + j] = acc[j] + bb[j];
    }
}

extern "C" void kernel_launch(void* const* d_in, const int* in_sizes, int n_in,
                              void* d_out, int out_size, void* d_ws, size_t ws_size,
                              hipStream_t stream) {
    const float* feat = (const float*)d_in[0];
    const float* W1   = (const float*)d_in[1];
    const float* g1   = (const float*)d_in[2];
    const float* b1   = (const float*)d_in[3];
    const float* W2   = (const float*)d_in[4];
    const float* g2   = (const float*)d_in[5];
    const float* b2   = (const float*)d_in[6];
    const float* caw1 = (const float*)d_in[7];
    const float* cab1 = (const float*)d_in[8];
    const float* caw2 = (const float*)d_in[9];
    const float* cab2 = (const float*)d_in[10];
    const float* saW  = (const float*)d_in[11];
    const float* clsw = (const float*)d_in[12];
    const float* clsb = (const float*)d_in[13];
    const int* p2v    = (const int*)d_in[14];
    const int* vb     = (const int*)d_in[15];
    const int* nidx   = (const int*)d_in[16];
    const void* nmask = d_in[17];
    float* out = (float*)d_out;

    int* flag   = (int*)d_ws;
    float* cnt  = (float*)d_ws + 64;              // 60000
    float* vox  = cnt + NVOX;                     // 240000 (sums -> averages in place)
    float* bsum = vox + (size_t)NVOX * 4;         // 128
    unsigned int* bmax = (unsigned int*)(bsum + NB * 32);  // 128
    float* bcnt = (float*)(bmax + NB * 32);       // 4
    float* ca   = bcnt + 64;                      // 128 (padded region)
    float* h1   = ca + 128;
    float* h2   = h1 + (size_t)NVOX * 32;
    float* s2   = h2 + (size_t)NVOX * 32;
    float* sa   = s2 + (size_t)NVOX * 2;

    int nzero = NVOX * 5 + NB * 32 * 2 + NB + 64;   // cnt..ca region
    k_init<<<512, 256, 0, stream>>>(cnt, nzero, (const unsigned int*)nmask, flag);
    k_scatter<<<(NPTS + 255) / 256, 256, 0, stream>>>((const float4*)feat, p2v, cnt, vox);
    k_voxdiv<<<(NVOX + 255) / 256, 256, 0, stream>>>(vox, cnt);
    k_conv1<<<(NVOX + 63) / 64, 256, 0, stream>>>(vox, W1, g1, b1, nidx, nmask, flag, h1);
    k_conv2<<<(NVOX + 63) / 64, 256, 0, stream>>>(h1, W2, g2, b2, nidx, nmask, flag, h2);
    k_pool<<<512, 256, 0, stream>>>(h2, vb, bsum, bmax, bcnt);
    k_ca<<<1, 64, 0, stream>>>(bsum, bmax, bcnt, caw1, cab1, caw2, cab2, ca);
    k_apply<<<(NVOX * 2 + 255) / 256, 256, 0, stream>>>(h2, ca, vb, s2);
    k_saconv<<<(NVOX * 4 + 255) / 256, 256, 0, stream>>>(s2, saW, nidx, nmask, flag, sa);
    k_final<<<(NPTS * 2 + 255) / 256, 256, 0, stream>>>(h2, sa, p2v, clsw, clsb, out);
}

// Round 14
// 218.640 us; speedup vs baseline: 1.0673x; 1.0673x over previous
//
#include <hip/hip_runtime.h>
#include <hip/hip_bf16.h>

#define NPTS 200000
#define NVOX 60000
#define NB 4
#define KK 27

// ---- mask encoding: 0 = uint8 bool, 1 = int32, 2 = float32 ----
__device__ __forceinline__ float get_mask(const void* nm, int fl, long i) {
    if (fl == 0) return ((const unsigned char*)nm)[i] ? 1.0f : 0.0f;
    if (fl == 1) return ((const int*)nm)[i] ? 1.0f : 0.0f;
    return ((const float*)nm)[i];
}

// bf16 helpers: RNE pack, bit-shift unpack
__device__ __forceinline__ unsigned bf16rn(float f) {
    unsigned u = __float_as_uint(f);
    u += 0x7fffu + ((u >> 16) & 1u);
    return u >> 16;
}
__device__ __forceinline__ float bflo(unsigned u) { return __uint_as_float(u << 16); }
__device__ __forceinline__ float bfhi(unsigned u) { return __uint_as_float(u & 0xffff0000u); }

// ---- init: zero scratch + detect mask encoding (block 0) ----
__global__ void k_init(float* zbase, int nz, const unsigned int* nm, int* flag) {
    for (int i = blockIdx.x * 256 + threadIdx.x; i < nz; i += gridDim.x * 256)
        zbase[i] = 0.f;
    if (blockIdx.x == 0) {
        __shared__ int cntF, cntI;
        if (threadIdx.x == 0) { cntF = 0; cntI = 0; }
        __syncthreads();
        int f = 0, i1 = 0;
        for (int i = threadIdx.x; i < 1024; i += 256) {
            unsigned int v = nm[i];
            if (v == 0x3f800000u) f++;
            if (v == 1u) i1++;
        }
        atomicAdd(&cntF, f); atomicAdd(&cntI, i1);
        __syncthreads();
        if (threadIdx.x == 0)
            *flag = (cntF > 100) ? 2 : ((cntI > 100) ? 1 : 0);
    }
}

// ---- voxelize: scatter-add points into voxels ----
__global__ void k_scatter(const float4* __restrict__ feat, const int* __restrict__ p2v,
                          float* cnt, float* vox) {
    int p = blockIdx.x * 256 + threadIdx.x;
    if (p >= NPTS) return;
    int v = p2v[p];
    float4 f = feat[p];
    atomicAdd(&cnt[v], 1.0f);
    atomicAdd(&vox[v * 4 + 0], f.x);
    atomicAdd(&vox[v * 4 + 1], f.y);
    atomicAdd(&vox[v * 4 + 2], f.z);
    atomicAdd(&vox[v * 4 + 3], f.w);
}

// ---- voxdiv: coalesced divide ----
__global__ void k_voxdiv(float* vox, const float* __restrict__ cnt) {
    int n = blockIdx.x * 256 + threadIdx.x;
    if (n >= NVOX) return;
    float inv = 1.0f / fmaxf(cnt[n], 1.0f);
    float4* vp = (float4*)(vox + n * 4);
    float4 v = *vp;
    v.x *= inv; v.y *= inv; v.z *= inv; v.w *= inv;
    *vp = v;
}

// ---- conv1: Cin=4 -> Cout=32; 256 thr = 64 vox x 4 kc-waves; h1 OUT in bf16 ----
__global__ __launch_bounds__(256) void k_conv1(
        const float* __restrict__ vox, const float* __restrict__ W1,
        const float* __restrict__ g1, const float* __restrict__ b1,
        const int* __restrict__ nidx, const void* __restrict__ nmask,
        const int* __restrict__ flag, unsigned* __restrict__ h1b) {
    __shared__ float part[3][64][33];
    int tid = threadIdx.x;
    int lane = tid & 63;
    int kc = __builtin_amdgcn_readfirstlane(tid >> 6);   // wave-uniform chunk
    int v = blockIdx.x * 64 + lane;
    int vc = v < NVOX ? v : NVOX - 1;
    int fl = *flag;
    int k0 = kc * 7;
    int k1 = (kc == 3) ? KK : k0 + 7;   // 7,7,7,6
    float acc[32];
#pragma unroll
    for (int d = 0; d < 32; d++) acc[d] = 0.f;
#pragma unroll 1
    for (int k = k0; k < k1; ++k) {
        int idx = nidx[k * NVOX + vc];
        float m = get_mask(nmask, fl, (long)k * NVOX + vc);
        float4 r = ((const float4*)vox)[idx];
        const float* wk = W1 + k * 128;   // wave-uniform -> s_load (3.4KB, K$-resident)
#pragma unroll
        for (int c = 0; c < 4; c++) {
            float rc = (c == 0 ? r.x : c == 1 ? r.y : c == 2 ? r.z : r.w) * m;
            const float* wc = wk + c * 32;
#pragma unroll
            for (int d = 0; d < 32; d++) acc[d] = fmaf(rc, wc[d], acc[d]);
        }
    }
    if (kc > 0) {
#pragma unroll
        for (int d = 0; d < 32; d++) part[kc - 1][lane][d] = acc[d];
    }
    __syncthreads();
    if (kc == 0 && v < NVOX) {
        unsigned pk[16];
#pragma unroll
        for (int i = 0; i < 16; i++) {
            float e0 = acc[2 * i]     + part[0][lane][2 * i]     + part[1][lane][2 * i]     + part[2][lane][2 * i];
            float e1 = acc[2 * i + 1] + part[0][lane][2 * i + 1] + part[1][lane][2 * i + 1] + part[2][lane][2 * i + 1];
            float o0 = fmaxf(e0 * g1[2 * i] + b1[2 * i], 0.f);
            float o1 = fmaxf(e1 * g1[2 * i + 1] + b1[2 * i + 1], 0.f);
            pk[i] = bf16rn(o0) | (bf16rn(o1) << 16);
        }
        uint4* op = (uint4*)(h1b + (size_t)v * 16);   // 64B row
#pragma unroll
        for (int qq = 0; qq < 4; qq++)
            op[qq] = make_uint4(pk[qq * 4], pk[qq * 4 + 1], pk[qq * 4 + 2], pk[qq * 4 + 3]);
    }
}

// ---- conv2: 512 thr = 8 waves (vhalf, kc); bf16 row gather (64B/row = 1 line) ----
// Six architectures plateaued 63-77us; r13 eliminated the scalar-weight path with
// no gain -> the wall is the TCP/L1-miss path on the RANDOM h1 gather (128 lines
// per wave-k, ~0% L1 hit). bf16 rows halve lines (1/row). Skeleton = r10 (best).
__global__ __launch_bounds__(512) void k_conv2(
        const unsigned* __restrict__ h1b, const float* __restrict__ W2,
        const float* __restrict__ g2, const float* __restrict__ b2,
        const int* __restrict__ nidx, const void* __restrict__ nmask,
        const int* __restrict__ flag, float* __restrict__ h2) {
    __shared__ float part[3][128][33];   // 50.7KB
    int tid = threadIdx.x;
    int lane = tid & 63;
    int wav = tid >> 6;
    int vhalf = __builtin_amdgcn_readfirstlane(wav & 1);   // wave-uniform
    int kc    = __builtin_amdgcn_readfirstlane(wav >> 1);  // wave-uniform
    int v = blockIdx.x * 128 + vhalf * 64 + lane;
    int vc = v < NVOX ? v : NVOX - 1;
    int fl = *flag;
    int k0 = kc * 7;
    int k1 = (kc == 3) ? KK : k0 + 7;   // 7,7,7,6
    float acc[32];
#pragma unroll
    for (int d = 0; d < 32; d++) acc[d] = 0.f;

#pragma unroll 1
    for (int k = k0; k < k1; ++k) {
        int idx = nidx[k * NVOX + vc];
        float m = get_mask(nmask, fl, (long)k * NVOX + vc);
        const uint4* rp = (const uint4*)(h1b + (size_t)idx * 16);   // 64B = 4 x uint4
        const float* wk = W2 + k * 1024;   // wave-uniform -> s_load
        uint4 q0 = rp[0], q1 = rp[1], q2 = rp[2], q3 = rp[3];
#pragma unroll
        for (int qq = 0; qq < 4; qq++) {
            uint4 q = (qq == 0) ? q0 : (qq == 1) ? q1 : (qq == 2) ? q2 : q3;
            float fv[8];
            fv[0] = bflo(q.x) * m; fv[1] = bfhi(q.x) * m;
            fv[2] = bflo(q.y) * m; fv[3] = bfhi(q.y) * m;
            fv[4] = bflo(q.z) * m; fv[5] = bfhi(q.z) * m;
            fv[6] = bflo(q.w) * m; fv[7] = bfhi(q.w) * m;
            const float* wq = wk + qq * 8 * 32;
#pragma unroll
            for (int c = 0; c < 8; c++) {
                float rc = fv[c];
                const float* wc = wq + c * 32;
#pragma unroll
                for (int d = 0; d < 32; d++) acc[d] = fmaf(rc, wc[d], acc[d]);
            }
        }
    }
    int row = vhalf * 64 + lane;
    if (kc > 0) {
#pragma unroll
        for (int d = 0; d < 32; d++) part[kc - 1][row][d] = acc[d];
    }
    __syncthreads();
    if (kc == 0 && v < NVOX) {
        float o[32];
#pragma unroll
        for (int d = 0; d < 32; d++) {
            float s = acc[d] + part[0][row][d] + part[1][row][d] + part[2][row][d];
            o[d] = fmaxf(s * g2[d] + b2[d], 0.f);
        }
        float4* op = (float4*)(h2 + (size_t)v * 32);
#pragma unroll
        for (int qq = 0; qq < 8; qq++)
            op[qq] = make_float4(o[qq * 4], o[qq * 4 + 1], o[qq * 4 + 2], o[qq * 4 + 3]);
    }
}

// ---- per-batch pooling: register accumulation, tiny atomic tail ----
__global__ __launch_bounds__(256) void k_pool(
        const float* __restrict__ h2, const int* __restrict__ vb,
        float* bsum, unsigned int* bmax, float* bcnt) {
    __shared__ float ls[NB * 32];
    __shared__ unsigned int lm[NB * 32];
    __shared__ float lc[NB];
    for (int i = threadIdx.x; i < NB * 32; i += 256) { ls[i] = 0.f; lm[i] = 0u; }
    if (threadIdx.x < NB) lc[threadIdx.x] = 0.f;
    __syncthreads();
    int c = threadIdx.x & 31, slot = threadIdx.x >> 5;
    float s0 = 0, s1 = 0, s2 = 0, s3 = 0, m0 = 0, m1 = 0, m2 = 0, m3 = 0;
    float c0 = 0, c1 = 0, c2 = 0, c3 = 0;
    for (int n = blockIdx.x * 8 + slot; n < NVOX; n += gridDim.x * 8) {
        float vv = h2[(size_t)n * 32 + c];
        int b = vb[n];
        s0 += (b == 0) ? vv : 0.f; m0 = (b == 0) ? fmaxf(m0, vv) : m0;
        s1 += (b == 1) ? vv : 0.f; m1 = (b == 1) ? fmaxf(m1, vv) : m1;
        s2 += (b == 2) ? vv : 0.f; m2 = (b == 2) ? fmaxf(m2, vv) : m2;
        s3 += (b == 3) ? vv : 0.f; m3 = (b == 3) ? fmaxf(m3, vv) : m3;
        if (c == 0) {
            c0 += (b == 0) ? 1.f : 0.f; c1 += (b == 1) ? 1.f : 0.f;
            c2 += (b == 2) ? 1.f : 0.f; c3 += (b == 3) ? 1.f : 0.f;
        }
    }
    atomicAdd(&ls[0 * 32 + c], s0); atomicAdd(&ls[1 * 32 + c], s1);
    atomicAdd(&ls[2 * 32 + c], s2); atomicAdd(&ls[3 * 32 + c], s3);
    atomicMax(&lm[0 * 32 + c], __float_as_uint(m0));  // h2 >= 0
    atomicMax(&lm[1 * 32 + c], __float_as_uint(m1));
    atomicMax(&lm[2 * 32 + c], __float_as_uint(m2));
    atomicMax(&lm[3 * 32 + c], __float_as_uint(m3));
    if (c == 0) {
        atomicAdd(&lc[0], c0); atomicAdd(&lc[1], c1);
        atomicAdd(&lc[2], c2); atomicAdd(&lc[3], c3);
    }
    __syncthreads();
    if (threadIdx.x < NB * 32) {
        atomicAdd(&bsum[threadIdx.x], ls[threadIdx.x]);
        atomicMax(&bmax[threadIdx.x], lm[threadIdx.x]);
    }
    if (threadIdx.x < NB) atomicAdd(&bcnt[threadIdx.x], lc[threadIdx.x]);
}

// ---- channel-attention MLP (tiny, 4 batches) ----
__global__ void k_ca(const float* __restrict__ bsum, const unsigned int* __restrict__ bmax,
                     const float* __restrict__ bcnt,
                     const float* __restrict__ w1, const float* __restrict__ b1,
                     const float* __restrict__ w2, const float* __restrict__ b2,
                     float* ca) {
    int b = threadIdx.x;
    if (b >= NB) return;
    float avg[32], mx[32], o[32];
    float inv = 1.0f / fmaxf(bcnt[b], 1.0f);
#pragma unroll
    for (int c = 0; c < 32; c++) {
        avg[c] = bsum[b * 32 + c] * inv;
        mx[c]  = __uint_as_float(bmax[b * 32 + c]);
        o[c] = 0.f;
    }
#pragma unroll
    for (int pass = 0; pass < 2; pass++) {
        float r[8];
#pragma unroll
        for (int j = 0; j < 8; j++) {
            float s = b1[j];
#pragma unroll
            for (int c = 0; c < 32; c++) s += (pass ? mx[c] : avg[c]) * w1[c * 8 + j];
            r[j] = fmaxf(s, 0.f);
        }
#pragma unroll
        for (int d = 0; d < 32; d++) {
            float s = b2[d];
#pragma unroll
            for (int j = 0; j < 8; j++) s += r[j] * w2[j * 32 + d];
            o[d] += s;
        }
    }
#pragma unroll
    for (int d = 0; d < 32; d++)
        ca[b * 32 + d] = 1.0f / (1.0f + expf(-o[d]));
}

// ---- apply channel attention (in place) + build s2 = [mean_c, max_c]; 2 thr/voxel ----
__global__ void k_apply(float* h2, const float* __restrict__ ca,
                        const int* __restrict__ vb, float* __restrict__ s2) {
    int t = blockIdx.x * 256 + threadIdx.x;
    int v = t >> 1, hf = t & 1;
    if (v >= NVOX) return;
    int b = vb[v];
    float4* hp = (float4*)(h2 + (size_t)v * 32) + hf * 4;
    const float4* cp = (const float4*)(ca + b * 32) + hf * 4;
    float sum = 0.f, mx = 0.f;
#pragma unroll
    for (int q = 0; q < 4; q++) {
        float4 h = hp[q]; float4 c = cp[q];
        h.x *= c.x; h.y *= c.y; h.z *= c.z; h.w *= c.w;
        hp[q] = h;
        sum += h.x + h.y + h.z + h.w;
        mx = fmaxf(mx, fmaxf(fmaxf(h.x, h.y), fmaxf(h.z, h.w)));
    }
    sum += __shfl_xor(sum, 1);
    mx = fmaxf(mx, __shfl_xor(mx, 1));
    if (hf == 0) {
        s2[v * 2 + 0] = sum * (1.0f / 32.0f);
        s2[v * 2 + 1] = mx;
    }
}

// ---- spatial attention: 2-ch sparse conv -> sigmoid; 4 thr/voxel ----
__global__ void k_saconv(const float* __restrict__ s2, const float* __restrict__ saW,
                         const int* __restrict__ nidx, const void* __restrict__ nmask,
                         const int* __restrict__ flag, float* __restrict__ sa) {
    __shared__ float w[KK * 2];
    if (threadIdx.x < KK * 2) w[threadIdx.x] = saW[threadIdx.x];
    __syncthreads();
    int t = blockIdx.x * 256 + threadIdx.x;
    int v = t >> 2, q = t & 3;
    if (v >= NVOX) return;
    int fl = *flag;
    float acc = 0.f;
#pragma unroll
    for (int j = 0; j < 7; j++) {
        int k = q + j * 4;
        if (k < KK) {
            int idx = nidx[k * NVOX + v];
            float m = get_mask(nmask, fl, (long)k * NVOX + v);
            float2 s = ((const float2*)s2)[idx];
            acc += m * (s.x * w[k * 2] + s.y * w[k * 2 + 1]);
        }
    }
    acc += __shfl_xor(acc, 1);
    acc += __shfl_xor(acc, 2);
    if (q == 0) sa[v] = 1.0f / (1.0f + expf(-acc));
}

// ---- gather to points, apply sa, classifier; 2 thr/point split over c ----
__global__ __launch_bounds__(256) void k_final(
        const float* __restrict__ h2, const float* __restrict__ sa,
        const int* __restrict__ p2v, const float* __restrict__ clsw,
        const float* __restrict__ clsb, float* __restrict__ out) {
    __shared__ float w[32 * 20];
    __shared__ float bb[20];
    for (int i = threadIdx.x; i < 640; i += 256) w[i] = clsw[i];
    if (threadIdx.x < 20) bb[threadIdx.x] = clsb[threadIdx.x];
    __syncthreads();
    int t = blockIdx.x * 256 + threadIdx.x;
    int p = t >> 1, ch = t & 1;
    if (p >= NPTS) return;
    int v = p2v[p];
    float s = sa[v];
    float acc[20];
#pragma unroll
    for (int j = 0; j < 20; j++) acc[j] = 0.f;
    const float4* hp = (const float4*)(h2 + (size_t)v * 32) + ch * 4;
#pragma unroll
    for (int q = 0; q < 4; q++) {
        float4 h = hp[q];
        int cb = (ch * 16 + q * 4) * 20;
        float z0 = h.x * s, z1 = h.y * s, z2 = h.z * s, z3 = h.w * s;
#pragma unroll
        for (int j = 0; j < 20; j++)
            acc[j] += z0 * w[cb + j] + z1 * w[cb + 20 + j]
                    + z2 * w[cb + 40 + j] + z3 * w[cb + 60 + j];
    }
#pragma unroll
    for (int j = 0; j < 20; j++) acc[j] += __shfl_xor(acc[j], 1);
    if (ch == 0) {
#pragma unroll
        for (int j = 0; j < 20; j++) out[(size_t)p * 20 + j] = acc[j] + bb[j];
    }
}

extern "C" void kernel_launch(void* const* d_in, const int* in_sizes, int n_in,
                              void* d_out, int out_size, void* d_ws, size_t ws_size,
                              hipStream_t stream) {
    const float* feat = (const float*)d_in[0];
    const float* W1   = (const float*)d_in[1];
    const float* g1   = (const float*)d_in[2];
    const float* b1   = (const float*)d_in[3];
    const float* W2   = (const float*)d_in[4];
    const float* g2   = (const float*)d_in[5];
    const float* b2   = (const float*)d_in[6];
    const float* caw1 = (const float*)d_in[7];
    const float* cab1 = (const float*)d_in[8];
    const float* caw2 = (const float*)d_in[9];
    const float* cab2 = (const float*)d_in[10];
    const float* saW  = (const float*)d_in[11];
    const float* clsw = (const float*)d_in[12];
    const float* clsb = (const float*)d_in[13];
    const int* p2v    = (const int*)d_in[14];
    const int* vb     = (const int*)d_in[15];
    const int* nidx   = (const int*)d_in[16];
    const void* nmask = d_in[17];
    float* out = (float*)d_out;

    int* flag   = (int*)d_ws;
    float* cnt  = (float*)d_ws + 64;              // 60000
    float* vox  = cnt + NVOX;                     // 240000 (sums -> averages in place)
    float* bsum = vox + (size_t)NVOX * 4;         // 128
    unsigned int* bmax = (unsigned int*)(bsum + NB * 32);  // 128
    float* bcnt = (float*)(bmax + NB * 32);       // 4
    float* ca   = bcnt + 64;                      // 128 (padded region)
    unsigned* h1b = (unsigned*)(ca + 128);        // bf16-packed: NVOX*16 uints
    float* h2   = (float*)(h1b + (size_t)NVOX * 16);
    float* s2   = h2 + (size_t)NVOX * 32;
    float* sa   = s2 + (size_t)NVOX * 2;

    int nzero = NVOX * 5 + NB * 32 * 2 + NB + 64;   // cnt..ca region
    k_init<<<512, 256, 0, stream>>>(cnt, nzero, (const unsigned int*)nmask, flag);
    k_scatter<<<(NPTS + 255) / 256, 256, 0, stream>>>((const float4*)feat, p2v, cnt, vox);
    k_voxdiv<<<(NVOX + 255) / 256, 256, 0, stream>>>(vox, cnt);
    k_conv1<<<(NVOX + 63) / 64, 256, 0, stream>>>(vox, W1, g1, b1, nidx, nmask, flag, h1b);
    k_conv2<<<(NVOX + 127) / 128, 512, 0, stream>>>(h1b, W2, g2, b2, nidx, nmask, flag, h2);
    k_pool<<<512, 256, 0, stream>>>(h2, vb, bsum, bmax, bcnt);
    k_ca<<<1, 64, 0, stream>>>(bsum, bmax, bcnt, caw1, cab1, caw2, cab2, ca);
    k_apply<<<(NVOX * 2 + 255) / 256, 256, 0, stream>>>(h2, ca, vb, s2);
    k_saconv<<<(NVOX * 4 + 255) / 256, 256, 0, stream>>>(s2, saW, nidx, nmask, flag, sa);
    k_final<<<(NPTS * 2 + 255) / 256, 256, 0, stream>>>(h2, sa, p2v, clsw, clsb, out);
}

// Round 15
// 215.721 us; speedup vs baseline: 1.0817x; 1.0135x over previous
//
#include <hip/hip_runtime.h>
#include <hip/hip_bf16.h>

#define NPTS 200000
#define NVOX 60000
#define NB 4
#define KK 27

// ---- mask encoding: 0 = uint8 bool, 1 = int32, 2 = float32 ----
__device__ __forceinline__ float get_mask(const void* nm, int fl, long i) {
    if (fl == 0) return ((const unsigned char*)nm)[i] ? 1.0f : 0.0f;
    if (fl == 1) return ((const int*)nm)[i] ? 1.0f : 0.0f;
    return ((const float*)nm)[i];
}

// bf16 helpers: RNE pack, bit-shift unpack
__device__ __forceinline__ unsigned bf16rn(float f) {
    unsigned u = __float_as_uint(f);
    u += 0x7fffu + ((u >> 16) & 1u);
    return u >> 16;
}
__device__ __forceinline__ float bflo(unsigned u) { return __uint_as_float(u << 16); }
__device__ __forceinline__ float bfhi(unsigned u) { return __uint_as_float(u & 0xffff0000u); }

// ---- init: zero scratch + detect mask encoding (block 0) ----
__global__ void k_init(float* zbase, int nz, const unsigned int* nm, int* flag) {
    for (int i = blockIdx.x * 256 + threadIdx.x; i < nz; i += gridDim.x * 256)
        zbase[i] = 0.f;
    if (blockIdx.x == 0) {
        __shared__ int cntF, cntI;
        if (threadIdx.x == 0) { cntF = 0; cntI = 0; }
        __syncthreads();
        int f = 0, i1 = 0;
        for (int i = threadIdx.x; i < 1024; i += 256) {
            unsigned int v = nm[i];
            if (v == 0x3f800000u) f++;
            if (v == 1u) i1++;
        }
        atomicAdd(&cntF, f); atomicAdd(&cntI, i1);
        __syncthreads();
        if (threadIdx.x == 0)
            *flag = (cntF > 100) ? 2 : ((cntI > 100) ? 1 : 0);
    }
}

// ---- voxelize: scatter-add points into voxels ----
__global__ void k_scatter(const float4* __restrict__ feat, const int* __restrict__ p2v,
                          float* cnt, float* vox) {
    int p = blockIdx.x * 256 + threadIdx.x;
    if (p >= NPTS) return;
    int v = p2v[p];
    float4 f = feat[p];
    atomicAdd(&cnt[v], 1.0f);
    atomicAdd(&vox[v * 4 + 0], f.x);
    atomicAdd(&vox[v * 4 + 1], f.y);
    atomicAdd(&vox[v * 4 + 2], f.z);
    atomicAdd(&vox[v * 4 + 3], f.w);
}

// ---- voxdiv: coalesced divide ----
__global__ void k_voxdiv(float* vox, const float* __restrict__ cnt) {
    int n = blockIdx.x * 256 + threadIdx.x;
    if (n >= NVOX) return;
    float inv = 1.0f / fmaxf(cnt[n], 1.0f);
    float4* vp = (float4*)(vox + n * 4);
    float4 v = *vp;
    v.x *= inv; v.y *= inv; v.z *= inv; v.w *= inv;
    *vp = v;
}

// ---- conv1: Cin=4 -> Cout=32; 256 thr = 64 vox x 4 kc-waves; h1 OUT in bf16 ----
__global__ __launch_bounds__(256) void k_conv1(
        const float* __restrict__ vox, const float* __restrict__ W1,
        const float* __restrict__ g1, const float* __restrict__ b1,
        const int* __restrict__ nidx, const void* __restrict__ nmask,
        const int* __restrict__ flag, unsigned* __restrict__ h1b) {
    __shared__ float part[3][64][33];
    int tid = threadIdx.x;
    int lane = tid & 63;
    int kc = __builtin_amdgcn_readfirstlane(tid >> 6);   // wave-uniform chunk
    int v = blockIdx.x * 64 + lane;
    int vc = v < NVOX ? v : NVOX - 1;
    int fl = *flag;
    int k0 = kc * 7;
    int k1 = (kc == 3) ? KK : k0 + 7;   // 7,7,7,6
    float acc[32];
#pragma unroll
    for (int d = 0; d < 32; d++) acc[d] = 0.f;
#pragma unroll 1
    for (int k = k0; k < k1; ++k) {
        int idx = nidx[k * NVOX + vc];
        float m = get_mask(nmask, fl, (long)k * NVOX + vc);
        float4 r = ((const float4*)vox)[idx];
        const float* wk = W1 + k * 128;   // wave-uniform -> s_load (3.4KB, K$-resident)
#pragma unroll
        for (int c = 0; c < 4; c++) {
            float rc = (c == 0 ? r.x : c == 1 ? r.y : c == 2 ? r.z : r.w) * m;
            const float* wc = wk + c * 32;
#pragma unroll
            for (int d = 0; d < 32; d++) acc[d] = fmaf(rc, wc[d], acc[d]);
        }
    }
    if (kc > 0) {
#pragma unroll
        for (int d = 0; d < 32; d++) part[kc - 1][lane][d] = acc[d];
    }
    __syncthreads();
    if (kc == 0 && v < NVOX) {
        unsigned pk[16];
#pragma unroll
        for (int i = 0; i < 16; i++) {
            float e0 = acc[2 * i]     + part[0][lane][2 * i]     + part[1][lane][2 * i]     + part[2][lane][2 * i];
            float e1 = acc[2 * i + 1] + part[0][lane][2 * i + 1] + part[1][lane][2 * i + 1] + part[2][lane][2 * i + 1];
            float o0 = fmaxf(e0 * g1[2 * i] + b1[2 * i], 0.f);
            float o1 = fmaxf(e1 * g1[2 * i + 1] + b1[2 * i + 1], 0.f);
            pk[i] = bf16rn(o0) | (bf16rn(o1) << 16);
        }
        uint4* op = (uint4*)(h1b + (size_t)v * 16);   // 64B row
#pragma unroll
        for (int qq = 0; qq < 4; qq++)
            op[qq] = make_uint4(pk[qq * 4], pk[qq * 4 + 1], pk[qq * 4 + 2], pk[qq * 4 + 3]);
    }
}

// ---- conv2: 512 thr = 8 waves (vhalf, kc); bf16 rows; NEXT-K GATHER PIPELINE;
//      per-batch pooling FUSED into epilogue (k_pool dispatch deleted) ----
// r14 null result: FETCH halved (bf16) but time unchanged -> LATENCY-bound, not
// throughput. Fix: prefetch next k's idx/mask/row (16 regs, fits the 64 clamp at
// VGPR=40 base) so the gather wait hides under current k's 2048 FMA cycles.
__global__ __launch_bounds__(512) void k_conv2(
        const unsigned* __restrict__ h1b, const float* __restrict__ W2,
        const float* __restrict__ g2, const float* __restrict__ b2,
        const int* __restrict__ nidx, const void* __restrict__ nmask,
        const int* __restrict__ flag, float* __restrict__ h2,
        const int* __restrict__ vb,
        float* bsum, unsigned int* bmax, float* bcnt) {
    __shared__ float part[3][128][33];   // 50.7KB
    __shared__ float ls[NB * 32];
    __shared__ unsigned lm[NB * 32];
    __shared__ float lc[NB];
    int tid = threadIdx.x;
    for (int i = tid; i < NB * 32; i += 512) { ls[i] = 0.f; lm[i] = 0u; }
    if (tid < NB) lc[tid] = 0.f;
    int lane = tid & 63;
    int wav = tid >> 6;
    int vhalf = __builtin_amdgcn_readfirstlane(wav & 1);   // wave-uniform
    int kc    = __builtin_amdgcn_readfirstlane(wav >> 1);  // wave-uniform
    int v = blockIdx.x * 128 + vhalf * 64 + lane;
    int vc = v < NVOX ? v : NVOX - 1;
    int fl = *flag;
    int k0 = kc * 7;
    int k1 = (kc == 3) ? KK : k0 + 7;   // 7,7,7,6
    float acc[32];
#pragma unroll
    for (int d = 0; d < 32; d++) acc[d] = 0.f;

    // prime k0's gather
    float mcur = get_mask(nmask, fl, (long)k0 * NVOX + vc);
    uint4 q0, q1, q2, q3;
    {
        int idx0 = nidx[k0 * NVOX + vc];
        const uint4* rp = (const uint4*)(h1b + (size_t)idx0 * 16);
        q0 = rp[0]; q1 = rp[1]; q2 = rp[2]; q3 = rp[3];
    }
#pragma unroll 1
    for (int k = k0; k < k1; ++k) {
        // prefetch next k's row while computing this one
        float mnxt = 0.f;
        uint4 n0, n1, n2, n3;
        if (k + 1 < k1) {
            int idxn = nidx[(k + 1) * NVOX + vc];
            mnxt = get_mask(nmask, fl, (long)(k + 1) * NVOX + vc);
            const uint4* rp = (const uint4*)(h1b + (size_t)idxn * 16);
            n0 = rp[0]; n1 = rp[1]; n2 = rp[2]; n3 = rp[3];
        } else {
            n0 = n1 = n2 = n3 = make_uint4(0u, 0u, 0u, 0u);
        }
        const float* wk = W2 + k * 1024;   // wave-uniform -> s_load
#pragma unroll
        for (int qq = 0; qq < 4; qq++) {
            uint4 q = (qq == 0) ? q0 : (qq == 1) ? q1 : (qq == 2) ? q2 : q3;
            float fv[8];
            fv[0] = bflo(q.x) * mcur; fv[1] = bfhi(q.x) * mcur;
            fv[2] = bflo(q.y) * mcur; fv[3] = bfhi(q.y) * mcur;
            fv[4] = bflo(q.z) * mcur; fv[5] = bfhi(q.z) * mcur;
            fv[6] = bflo(q.w) * mcur; fv[7] = bfhi(q.w) * mcur;
            const float* wq = wk + qq * 8 * 32;
#pragma unroll
            for (int c = 0; c < 8; c++) {
                float rc = fv[c];
                const float* wc = wq + c * 32;
#pragma unroll
                for (int d = 0; d < 32; d++) acc[d] = fmaf(rc, wc[d], acc[d]);
            }
        }
        q0 = n0; q1 = n1; q2 = n2; q3 = n3;
        mcur = mnxt;
    }
    int row = vhalf * 64 + lane;
    if (kc > 0) {
#pragma unroll
        for (int d = 0; d < 32; d++) part[kc - 1][row][d] = acc[d];
    }
    __syncthreads();
    if (kc == 0 && v < NVOX) {
        float o[32];
#pragma unroll
        for (int d = 0; d < 32; d++) {
            float s = acc[d] + part[0][row][d] + part[1][row][d] + part[2][row][d];
            o[d] = fmaxf(s * g2[d] + b2[d], 0.f);
        }
        float4* op = (float4*)(h2 + (size_t)v * 32);
#pragma unroll
        for (int qq = 0; qq < 8; qq++)
            op[qq] = make_float4(o[qq * 4], o[qq * 4 + 1], o[qq * 4 + 2], o[qq * 4 + 3]);
        // fused per-batch pooling of this block's own voxels
        int b = vb[v];
        atomicAdd(&lc[b], 1.0f);
#pragma unroll
        for (int d = 0; d < 32; d++) {
            atomicAdd(&ls[b * 32 + d], o[d]);
            atomicMax(&lm[b * 32 + d], __float_as_uint(o[d]));  // o >= 0
        }
    }
    __syncthreads();
    if (tid < NB * 32) {
        atomicAdd(&bsum[tid], ls[tid]);
        atomicMax(&bmax[tid], lm[tid]);
    }
    if (tid < NB) atomicAdd(&bcnt[tid], lc[tid]);
}

// ---- channel-attention MLP (tiny, 4 batches) ----
__global__ void k_ca(const float* __restrict__ bsum, const unsigned int* __restrict__ bmax,
                     const float* __restrict__ bcnt,
                     const float* __restrict__ w1, const float* __restrict__ b1,
                     const float* __restrict__ w2, const float* __restrict__ b2,
                     float* ca) {
    int b = threadIdx.x;
    if (b >= NB) return;
    float avg[32], mx[32], o[32];
    float inv = 1.0f / fmaxf(bcnt[b], 1.0f);
#pragma unroll
    for (int c = 0; c < 32; c++) {
        avg[c] = bsum[b * 32 + c] * inv;
        mx[c]  = __uint_as_float(bmax[b * 32 + c]);
        o[c] = 0.f;
    }
#pragma unroll
    for (int pass = 0; pass < 2; pass++) {
        float r[8];
#pragma unroll
        for (int j = 0; j < 8; j++) {
            float s = b1[j];
#pragma unroll
            for (int c = 0; c < 32; c++) s += (pass ? mx[c] : avg[c]) * w1[c * 8 + j];
            r[j] = fmaxf(s, 0.f);
        }
#pragma unroll
        for (int d = 0; d < 32; d++) {
            float s = b2[d];
#pragma unroll
            for (int j = 0; j < 8; j++) s += r[j] * w2[j * 32 + d];
            o[d] += s;
        }
    }
#pragma unroll
    for (int d = 0; d < 32; d++)
        ca[b * 32 + d] = 1.0f / (1.0f + expf(-o[d]));
}

// ---- apply channel attention (in place) + build s2 = [mean_c, max_c]; 2 thr/voxel ----
__global__ void k_apply(float* h2, const float* __restrict__ ca,
                        const int* __restrict__ vb, float* __restrict__ s2) {
    int t = blockIdx.x * 256 + threadIdx.x;
    int v = t >> 1, hf = t & 1;
    if (v >= NVOX) return;
    int b = vb[v];
    float4* hp = (float4*)(h2 + (size_t)v * 32) + hf * 4;
    const float4* cp = (const float4*)(ca + b * 32) + hf * 4;
    float sum = 0.f, mx = 0.f;
#pragma unroll
    for (int q = 0; q < 4; q++) {
        float4 h = hp[q]; float4 c = cp[q];
        h.x *= c.x; h.y *= c.y; h.z *= c.z; h.w *= c.w;
        hp[q] = h;
        sum += h.x + h.y + h.z + h.w;
        mx = fmaxf(mx, fmaxf(fmaxf(h.x, h.y), fmaxf(h.z, h.w)));
    }
    sum += __shfl_xor(sum, 1);
    mx = fmaxf(mx, __shfl_xor(mx, 1));
    if (hf == 0) {
        s2[v * 2 + 0] = sum * (1.0f / 32.0f);
        s2[v * 2 + 1] = mx;
    }
}

// ---- spatial attention: 2-ch sparse conv -> sigmoid; 4 thr/voxel ----
__global__ void k_saconv(const float* __restrict__ s2, const float* __restrict__ saW,
                         const int* __restrict__ nidx, const void* __restrict__ nmask,
                         const int* __restrict__ flag, float* __restrict__ sa) {
    __shared__ float w[KK * 2];
    if (threadIdx.x < KK * 2) w[threadIdx.x] = saW[threadIdx.x];
    __syncthreads();
    int t = blockIdx.x * 256 + threadIdx.x;
    int v = t >> 2, q = t & 3;
    if (v >= NVOX) return;
    int fl = *flag;
    float acc = 0.f;
#pragma unroll
    for (int j = 0; j < 7; j++) {
        int k = q + j * 4;
        if (k < KK) {
            int idx = nidx[k * NVOX + v];
            float m = get_mask(nmask, fl, (long)k * NVOX + v);
            float2 s = ((const float2*)s2)[idx];
            acc += m * (s.x * w[k * 2] + s.y * w[k * 2 + 1]);
        }
    }
    acc += __shfl_xor(acc, 1);
    acc += __shfl_xor(acc, 2);
    if (q == 0) sa[v] = 1.0f / (1.0f + expf(-acc));
}

// ---- gather to points, apply sa, classifier; 2 thr/point split over c ----
__global__ __launch_bounds__(256) void k_final(
        const float* __restrict__ h2, const float* __restrict__ sa,
        const int* __restrict__ p2v, const float* __restrict__ clsw,
        const float* __restrict__ clsb, float* __restrict__ out) {
    __shared__ float w[32 * 20];
    __shared__ float bb[20];
    for (int i = threadIdx.x; i < 640; i += 256) w[i] = clsw[i];
    if (threadIdx.x < 20) bb[threadIdx.x] = clsb[threadIdx.x];
    __syncthreads();
    int t = blockIdx.x * 256 + threadIdx.x;
    int p = t >> 1, ch = t & 1;
    if (p >= NPTS) return;
    int v = p2v[p];
    float s = sa[v];
    float acc[20];
#pragma unroll
    for (int j = 0; j < 20; j++) acc[j] = 0.f;
    const float4* hp = (const float4*)(h2 + (size_t)v * 32) + ch * 4;
#pragma unroll
    for (int q = 0; q < 4; q++) {
        float4 h = hp[q];
        int cb = (ch * 16 + q * 4) * 20;
        float z0 = h.x * s, z1 = h.y * s, z2 = h.z * s, z3 = h.w * s;
#pragma unroll
        for (int j = 0; j < 20; j++)
            acc[j] += z0 * w[cb + j] + z1 * w[cb + 20 + j]
                    + z2 * w[cb + 40 + j] + z3 * w[cb + 60 + j];
    }
#pragma unroll
    for (int j = 0; j < 20; j++) acc[j] += __shfl_xor(acc[j], 1);
    if (ch == 0) {
#pragma unroll
        for (int j = 0; j < 20; j++) out[(size_t)p * 20 + j] = acc[j] + bb[j];
    }
}

extern "C" void kernel_launch(void* const* d_in, const int* in_sizes, int n_in,
                              void* d_out, int out_size, void* d_ws, size_t ws_size,
                              hipStream_t stream) {
    const float* feat = (const float*)d_in[0];
    const float* W1   = (const float*)d_in[1];
    const float* g1   = (const float*)d_in[2];
    const float* b1   = (const float*)d_in[3];
    const float* W2   = (const float*)d_in[4];
    const float* g2   = (const float*)d_in[5];
    const float* b2   = (const float*)d_in[6];
    const float* caw1 = (const float*)d_in[7];
    const float* cab1 = (const float*)d_in[8];
    const float* caw2 = (const float*)d_in[9];
    const float* cab2 = (const float*)d_in[10];
    const float* saW  = (const float*)d_in[11];
    const float* clsw = (const float*)d_in[12];
    const float* clsb = (const float*)d_in[13];
    const int* p2v    = (const int*)d_in[14];
    const int* vb     = (const int*)d_in[15];
    const int* nidx   = (const int*)d_in[16];
    const void* nmask = d_in[17];
    float* out = (float*)d_out;

    int* flag   = (int*)d_ws;
    float* cnt  = (float*)d_ws + 64;              // 60000
    float* vox  = cnt + NVOX;                     // 240000 (sums -> averages in place)
    float* bsum = vox + (size_t)NVOX * 4;         // 128
    unsigned int* bmax = (unsigned int*)(bsum + NB * 32);  // 128
    float* bcnt = (float*)(bmax + NB * 32);       // 4
    float* ca   = bcnt + 64;                      // 128 (padded region)
    unsigned* h1b = (unsigned*)(ca + 128);        // bf16-packed: NVOX*16 uints
    float* h2   = (float*)(h1b + (size_t)NVOX * 16);
    float* s2   = h2 + (size_t)NVOX * 32;
    float* sa   = s2 + (size_t)NVOX * 2;

    int nzero = NVOX * 5 + NB * 32 * 2 + NB + 64;   // cnt..ca region
    k_init<<<512, 256, 0, stream>>>(cnt, nzero, (const unsigned int*)nmask, flag);
    k_scatter<<<(NPTS + 255) / 256, 256, 0, stream>>>((const float4*)feat, p2v, cnt, vox);
    k_voxdiv<<<(NVOX + 255) / 256, 256, 0, stream>>>(vox, cnt);
    k_conv1<<<(NVOX + 63) / 64, 256, 0, stream>>>(vox, W1, g1, b1, nidx, nmask, flag, h1b);
    k_conv2<<<(NVOX + 127) / 128, 512, 0, stream>>>(h1b, W2, g2, b2, nidx, nmask, flag, h2,
                                                    vb, bsum, bmax, bcnt);
    k_ca<<<1, 64, 0, stream>>>(bsum, bmax, bcnt, caw1, cab1, caw2, cab2, ca);
    k_apply<<<(NVOX * 2 + 255) / 256, 256, 0, stream>>>(h2, ca, vb, s2);
    k_saconv<<<(NVOX * 4 + 255) / 256, 256, 0, stream>>>(s2, saW, nidx, nmask, flag, sa);
    k_final<<<(NPTS * 2 + 255) / 256, 256, 0, stream>>>(h2, sa, p2v, clsw, clsb, out);
}